// Round 1
// baseline (415.956 us; speedup 1.0000x reference)
//
#include <hip/hip_runtime.h>

// B=4, N=2048, F=1024, H=16, D=64.  All dims hard-coded.
#define LOG2E 1.44269504088896340736f

typedef float f32x4 __attribute__((ext_vector_type(4)));
typedef __bf16 bf16x8 __attribute__((ext_vector_type(8)));

__device__ __forceinline__ unsigned short f2bf(float f){
  unsigned int u = __builtin_bit_cast(unsigned int, f);
  u += 0x7fffu + ((u >> 16) & 1u);          // RNE
  return (unsigned short)(u >> 16);
}

__device__ __forceinline__ void gload_lds16(const void* g, void* l){
  __builtin_amdgcn_global_load_lds(
      (const __attribute__((address_space(1))) unsigned int*)g,
      (__attribute__((address_space(3))) unsigned int*)l, 16, 0, 0);
}

// ---- x (fp32 [8192][1024]) -> bf16, 128B-block swizzled: byte ^= ((row&7)<<4)
__global__ __launch_bounds__(256) void cvt_x(const float* __restrict__ x,
                                             unsigned short* __restrict__ xs){
  int t = blockIdx.x * 256 + threadIdx.x;   // 1,048,576 chunks of 8 elems
  int m = t >> 7, c = t & 127;
  const float4* p = (const float4*)(x + ((size_t)m << 10) + (c << 3));
  float4 f0 = p[0], f1 = p[1];
  unsigned int w0 = f2bf(f0.x) | ((unsigned int)f2bf(f0.y) << 16);
  unsigned int w1 = f2bf(f0.z) | ((unsigned int)f2bf(f0.w) << 16);
  unsigned int w2 = f2bf(f1.x) | ((unsigned int)f2bf(f1.y) << 16);
  unsigned int w3 = f2bf(f1.z) | ((unsigned int)f2bf(f1.w) << 16);
  int byte = (c << 4) ^ ((m & 7) << 4);
  *(uint4*)((char*)xs + ((size_t)m << 11) + byte) = make_uint4(w0, w1, w2, w3);
}

// ---- W (fp32 [1024k][1024n]) -> bf16 transposed Wt[n][k], same swizzle by n
__global__ __launch_bounds__(256) void cvt_w(const float* __restrict__ Wq,
                                             const float* __restrict__ Wk,
                                             const float* __restrict__ Wv,
                                             unsigned short* __restrict__ wtq,
                                             unsigned short* __restrict__ wtk,
                                             unsigned short* __restrict__ wtv){
  int t = blockIdx.x * 256 + threadIdx.x;   // 131072 per matrix
  int n = t & 1023, c = t >> 10;            // c = k-chunk (8 k's)
  const float* W = blockIdx.y == 0 ? Wq : blockIdx.y == 1 ? Wk : Wv;
  unsigned short* o = blockIdx.y == 0 ? wtq : blockIdx.y == 1 ? wtk : wtv;
  unsigned int w[4];
  #pragma unroll
  for (int i = 0; i < 4; ++i){
    float a = W[(size_t)(c * 8 + 2 * i) * 1024 + n];
    float b = W[(size_t)(c * 8 + 2 * i + 1) * 1024 + n];
    w[i] = f2bf(a) | ((unsigned int)f2bf(b) << 16);
  }
  int byte = (c << 4) ^ ((n & 7) << 4);
  *(uint4*)((char*)o + ((size_t)n << 11) + byte) = make_uint4(w[0], w[1], w[2], w[3]);
}

// ---- projection GEMM: C[8192][1024] = xs @ Wt^T (+bias). z picks Q/K/V.
// 128x128 tile, BK=64, 4 waves, global_load_lds(16B), swizzled ds_read_b128.
// Q: scaled by 0.125, layout [b,h,n,d]. K: [b,h,n,d]. V: transposed [b,h,d,n].
__global__ __launch_bounds__(256) void proj_gemm(
    const unsigned short* __restrict__ xs,
    const unsigned short* __restrict__ wt0, const unsigned short* __restrict__ wt1,
    const unsigned short* __restrict__ wt2,
    const float* __restrict__ b0, const float* __restrict__ b1, const float* __restrict__ b2,
    unsigned short* __restrict__ o0, unsigned short* __restrict__ o1,
    unsigned short* __restrict__ o2){
  __shared__ char As[16384];
  __shared__ char Bs[16384];
  const int v = blockIdx.z;
  const unsigned short* wt = v == 0 ? wt0 : v == 1 ? wt1 : wt2;
  const float* bias = v == 0 ? b0 : v == 1 ? b1 : b2;
  const int row0 = blockIdx.x << 7;
  const int col0 = blockIdx.y << 7;
  const int tid = threadIdx.x;
  const int wave = tid >> 6, lane = tid & 63;
  const int wr = wave >> 1, wc = wave & 1;
  f32x4 acc[4][4] = {};

  const char* abase = (const char*)xs + (size_t)(row0 + wave * 8 + (lane >> 3)) * 2048 + ((lane & 7) << 4);
  const char* bbase = (const char*)wt + (size_t)(col0 + wave * 8 + (lane >> 3)) * 2048 + ((lane & 7) << 4);
  char* aldst = As + wave * 1024;
  char* bldst = Bs + wave * 1024;

  for (int kk = 0; kk < 16; ++kk){
    const size_t koff = (size_t)kk << 7;
    #pragma unroll
    for (int c = 0; c < 4; ++c){
      gload_lds16(abase + (size_t)c * 65536 + koff, aldst + c * 4096);
      gload_lds16(bbase + (size_t)c * 65536 + koff, bldst + c * 4096);
    }
    __syncthreads();
    #pragma unroll
    for (int s = 0; s < 2; ++s){
      bf16x8 af[4], bfr[4];
      #pragma unroll
      for (int mt = 0; mt < 4; ++mt){
        int r = wr * 64 + mt * 16 + (lane & 15);
        int byte = (((lane >> 4) << 4) + (s << 6)) ^ ((r & 7) << 4);
        af[mt] = *(const bf16x8*)(As + r * 128 + byte);
      }
      #pragma unroll
      for (int nt = 0; nt < 4; ++nt){
        int cc = wc * 64 + nt * 16 + (lane & 15);
        int byte = (((lane >> 4) << 4) + (s << 6)) ^ ((cc & 7) << 4);
        bfr[nt] = *(const bf16x8*)(Bs + cc * 128 + byte);
      }
      #pragma unroll
      for (int mt = 0; mt < 4; ++mt)
        #pragma unroll
        for (int nt = 0; nt < 4; ++nt)
          acc[mt][nt] = __builtin_amdgcn_mfma_f32_16x16x32_bf16(af[mt], bfr[nt], acc[mt][nt], 0, 0, 0);
    }
    __syncthreads();
  }

  #pragma unroll
  for (int nt = 0; nt < 4; ++nt){
    int col = col0 + wc * 64 + nt * 16 + (lane & 15);
    float bia = bias[col];
    int h = col >> 6, d = col & 63;
    #pragma unroll
    for (int mt = 0; mt < 4; ++mt){
      #pragma unroll
      for (int r = 0; r < 4; ++r){
        int mrow = row0 + wr * 64 + mt * 16 + ((lane >> 4) << 2) + r;
        int b = mrow >> 11, n = mrow & 2047;
        float val = acc[mt][nt][r] + bia;
        if (v == 0){        // Q, scaled by 1/sqrt(D)=0.125 (exact in bf16)
          o0[((size_t)((b * 16 + h) * 2048 + n) << 6) + d] = f2bf(val * 0.125f);
        } else if (v == 1){ // K
          o1[((size_t)((b * 16 + h) * 2048 + n) << 6) + d] = f2bf(val);
        } else {            // V transposed: [b,h,d,n]
          o2[((size_t)((b * 16 + h) * 64 + d) << 11) + n] = f2bf(val);
        }
      }
    }
  }
}

// ---- causal flash attention. 4 waves x 16 q-rows = QBLK 64; KVBLK 64.
// K/V direct from global (L1/L2-resident tiles); P via per-wave swizzled LDS.
__global__ __launch_bounds__(256) void attn(
    const unsigned short* __restrict__ Qg, const unsigned short* __restrict__ Kg,
    const unsigned short* __restrict__ Vt, float* __restrict__ out){
  const int bh = blockIdx.x;                 // b*16+h
  const int qt = 31 - (int)blockIdx.y;       // heaviest q-tiles dispatch first
  const int wave = threadIdx.x >> 6, lane = threadIdx.x & 63;
  __shared__ char Plds[4][2048];
  char* pb = Plds[wave];
  const int q0 = qt << 6;
  const int l15 = lane & 15, lg = lane >> 4;
  const unsigned short* qb = Qg + ((size_t)bh << 17);
  const unsigned short* kb = Kg + ((size_t)bh << 17);
  const unsigned short* vb = Vt + ((size_t)bh << 17);

  bf16x8 aq[2];
  #pragma unroll
  for (int s = 0; s < 2; ++s)
    aq[s] = *(const bf16x8*)(qb + (size_t)(q0 + wave * 16 + l15) * 64 + lg * 8 + s * 32);

  float m_[4], ls[4];
  f32x4 o[4] = {};
  #pragma unroll
  for (int r = 0; r < 4; ++r){ m_[r] = -1e30f; ls[r] = 0.f; }

  for (int kt = 0; kt <= qt; ++kt){
    const bool diag = (kt == qt);
    const int ntmax = diag ? (wave + 1) : 4;
    f32x4 sacc[4] = {};
    #pragma unroll
    for (int nt = 0; nt < 4; ++nt){
      if (nt < ntmax){
        #pragma unroll
        for (int s = 0; s < 2; ++s){
          bf16x8 kf = *(const bf16x8*)(kb + (size_t)(kt * 64 + nt * 16 + l15) * 64 + lg * 8 + s * 32);
          sacc[nt] = __builtin_amdgcn_mfma_f32_16x16x32_bf16(aq[s], kf, sacc[nt], 0, 0, 0);
        }
      }
    }
    float tmax[4] = {-1e30f, -1e30f, -1e30f, -1e30f};
    #pragma unroll
    for (int nt = 0; nt < 4; ++nt){
      if (nt < ntmax){
        #pragma unroll
        for (int r = 0; r < 4; ++r){
          float sv = sacc[nt][r];
          if (diag){
            int kcol = kt * 64 + nt * 16 + l15;
            int qr = q0 + wave * 16 + lg * 4 + r;
            if (kcol > qr) sv = -1e30f;
          }
          sacc[nt][r] = sv;
          tmax[r] = fmaxf(tmax[r], sv);
        }
      }
    }
    #pragma unroll
    for (int r = 0; r < 4; ++r){
      #pragma unroll
      for (int off = 1; off < 16; off <<= 1)
        tmax[r] = fmaxf(tmax[r], __shfl_xor(tmax[r], off));
    }
    float corr[4], rs[4] = {0.f, 0.f, 0.f, 0.f};
    #pragma unroll
    for (int r = 0; r < 4; ++r){
      float mn = fmaxf(m_[r], tmax[r]);
      corr[r] = exp2f((m_[r] - mn) * LOG2E);
      m_[r] = mn;
    }
    float p[4][4];
    #pragma unroll
    for (int nt = 0; nt < 4; ++nt){
      #pragma unroll
      for (int r = 0; r < 4; ++r){
        float pv = 0.f;
        if (nt < ntmax) pv = exp2f((sacc[nt][r] - m_[r]) * LOG2E);
        p[nt][r] = pv;
        rs[r] += pv;
      }
    }
    #pragma unroll
    for (int r = 0; r < 4; ++r){
      #pragma unroll
      for (int off = 1; off < 16; off <<= 1)
        rs[r] += __shfl_xor(rs[r], off);
      ls[r] = ls[r] * corr[r] + rs[r];
    }
    #pragma unroll
    for (int f = 0; f < 4; ++f)
      #pragma unroll
      for (int r = 0; r < 4; ++r)
        o[f][r] *= corr[r];
    // P -> LDS (bf16, XOR-swizzled rows)
    #pragma unroll
    for (int nt = 0; nt < 4; ++nt){
      #pragma unroll
      for (int r = 0; r < 4; ++r){
        int row = lg * 4 + r;
        int byte = ((nt * 16 + l15) << 1) ^ ((row & 7) << 4);
        *(unsigned short*)(pb + row * 128 + byte) = f2bf(p[nt][r]);
      }
    }
    const int kslim = diag ? (wave / 2 + 1) : 2;
    #pragma unroll
    for (int ks = 0; ks < 2; ++ks){
      if (ks < kslim){
        int pbyte = ((lg << 4) + (ks << 6)) ^ ((l15 & 7) << 4);
        bf16x8 pa = *(const bf16x8*)(pb + l15 * 128 + pbyte);
        #pragma unroll
        for (int f = 0; f < 4; ++f){
          bf16x8 vf = *(const bf16x8*)(vb + (size_t)(f * 16 + l15) * 2048 + kt * 64 + ks * 32 + lg * 8);
          o[f] = __builtin_amdgcn_mfma_f32_16x16x32_bf16(pa, vf, o[f], 0, 0, 0);
        }
      }
    }
  }
  const int b = bh >> 4, h = bh & 15;
  #pragma unroll
  for (int r = 0; r < 4; ++r){
    float inv = 1.f / ls[r];
    int qrow = q0 + wave * 16 + lg * 4 + r;
    float* op = out + ((size_t)(b * 2048 + qrow) << 10) + h * 64 + l15;
    #pragma unroll
    for (int f = 0; f < 4; ++f)
      op[f * 16] = o[f][r] * inv;
  }
}

extern "C" void kernel_launch(void* const* d_in, const int* in_sizes, int n_in,
                              void* d_out, int out_size, void* d_ws, size_t ws_size,
                              hipStream_t stream){
  const float* x  = (const float*)d_in[0];
  const float* Wq = (const float*)d_in[1];
  const float* bq = (const float*)d_in[2];
  const float* Wk = (const float*)d_in[3];
  const float* bk = (const float*)d_in[4];
  const float* Wv = (const float*)d_in[5];
  const float* bv = (const float*)d_in[6];
  float* out = (float*)d_out;
  char* ws = (char*)d_ws;
  // ws layout (bytes): xs 16MB | wtq/wtk/wtv 2MB each | Q 16MB | K 16MB | Vt 16MB = 70MB
  unsigned short* xs  = (unsigned short*)(ws);
  unsigned short* wtq = (unsigned short*)(ws + 16777216);
  unsigned short* wtk = (unsigned short*)(ws + 18874368);
  unsigned short* wtv = (unsigned short*)(ws + 20971520);
  unsigned short* Qg  = (unsigned short*)(ws + 23068672);
  unsigned short* Kg  = (unsigned short*)(ws + 39845888);
  unsigned short* Vt  = (unsigned short*)(ws + 56623104);

  cvt_x<<<4096, 256, 0, stream>>>(x, xs);
  cvt_w<<<dim3(512, 3), 256, 0, stream>>>(Wq, Wk, Wv, wtq, wtk, wtv);
  proj_gemm<<<dim3(64, 8, 3), 256, 0, stream>>>(xs, wtq, wtk, wtv, bq, bk, bv, Qg, Kg, Vt);
  attn<<<dim3(64, 32), 256, 0, stream>>>(Qg, Kg, Vt, out);
}

// Round 6
// 303.946 us; speedup vs baseline: 1.3685x; 1.3685x over previous
//
#include <hip/hip_runtime.h>

// B=4, N=2048, F=1024, H=16, D=64.  All dims hard-coded.
#define LOG2E 1.44269504088896340736f

typedef float f32x4 __attribute__((ext_vector_type(4)));
typedef float f32x16 __attribute__((ext_vector_type(16)));
typedef __bf16 bf16x8 __attribute__((ext_vector_type(8)));

__device__ __forceinline__ unsigned short f2bf(float f){
  unsigned int u = __builtin_bit_cast(unsigned int, f);
  u += 0x7fffu + ((u >> 16) & 1u);          // RNE
  return (unsigned short)(u >> 16);
}

__device__ __forceinline__ void gload_lds16(const void* g, void* l){
  __builtin_amdgcn_global_load_lds(
      (const __attribute__((address_space(1))) unsigned int*)g,
      (__attribute__((address_space(3))) unsigned int*)l, 16, 0, 0);
}

// ---- x (fp32 [8192][1024]) -> bf16, 128B-block swizzled: byte ^= ((row&7)<<4)
__global__ __launch_bounds__(256) void cvt_x(const float* __restrict__ x,
                                             unsigned short* __restrict__ xs){
  int t = blockIdx.x * 256 + threadIdx.x;   // 1,048,576 chunks of 8 elems
  int m = t >> 7, c = t & 127;
  const float4* p = (const float4*)(x + ((size_t)m << 10) + (c << 3));
  float4 f0 = p[0], f1 = p[1];
  unsigned int w0 = f2bf(f0.x) | ((unsigned int)f2bf(f0.y) << 16);
  unsigned int w1 = f2bf(f0.z) | ((unsigned int)f2bf(f0.w) << 16);
  unsigned int w2 = f2bf(f1.x) | ((unsigned int)f2bf(f1.y) << 16);
  unsigned int w3 = f2bf(f1.z) | ((unsigned int)f2bf(f1.w) << 16);
  int byte = (c << 4) ^ ((m & 7) << 4);
  *(uint4*)((char*)xs + ((size_t)m << 11) + byte) = make_uint4(w0, w1, w2, w3);
}

// ---- W (fp32 [1024k][1024n]) -> bf16 transposed Wt[n][k], same swizzle by n
__global__ __launch_bounds__(256) void cvt_w(const float* __restrict__ Wq,
                                             const float* __restrict__ Wk,
                                             const float* __restrict__ Wv,
                                             unsigned short* __restrict__ wtq,
                                             unsigned short* __restrict__ wtk,
                                             unsigned short* __restrict__ wtv){
  int t = blockIdx.x * 256 + threadIdx.x;   // 131072 per matrix
  int n = t & 1023, c = t >> 10;            // c = k-chunk (8 k's)
  const float* W = blockIdx.y == 0 ? Wq : blockIdx.y == 1 ? Wk : Wv;
  unsigned short* o = blockIdx.y == 0 ? wtq : blockIdx.y == 1 ? wtk : wtv;
  unsigned int w[4];
  #pragma unroll
  for (int i = 0; i < 4; ++i){
    float a = W[(size_t)(c * 8 + 2 * i) * 1024 + n];
    float b = W[(size_t)(c * 8 + 2 * i + 1) * 1024 + n];
    w[i] = f2bf(a) | ((unsigned int)f2bf(b) << 16);
  }
  int byte = (c << 4) ^ ((n & 7) << 4);
  *(uint4*)((char*)o + ((size_t)n << 11) + byte) = make_uint4(w[0], w[1], w[2], w[3]);
}

// ---- projection GEMM: C[8192][1024] = xs @ Wt^T (+bias). z picks Q/K/V.
// 128x128 tile, BK=64, 4 waves, global_load_lds(16B), swizzled ds_read_b128.
// Q: scaled by 0.125, layout [b,h,n,d]. K: [b,h,n,d]. V: transposed [b,h,d,n].
__global__ __launch_bounds__(256) void proj_gemm(
    const unsigned short* __restrict__ xs,
    const unsigned short* __restrict__ wt0, const unsigned short* __restrict__ wt1,
    const unsigned short* __restrict__ wt2,
    const float* __restrict__ b0, const float* __restrict__ b1, const float* __restrict__ b2,
    unsigned short* __restrict__ o0, unsigned short* __restrict__ o1,
    unsigned short* __restrict__ o2){
  __shared__ char As[16384];
  __shared__ char Bs[16384];
  const int v = blockIdx.z;
  const unsigned short* wt = v == 0 ? wt0 : v == 1 ? wt1 : wt2;
  const float* bias = v == 0 ? b0 : v == 1 ? b1 : b2;
  const int row0 = blockIdx.x << 7;
  const int col0 = blockIdx.y << 7;
  const int tid = threadIdx.x;
  const int wave = tid >> 6, lane = tid & 63;
  const int wr = wave >> 1, wc = wave & 1;
  f32x4 acc[4][4] = {};

  const char* abase = (const char*)xs + (size_t)(row0 + wave * 8 + (lane >> 3)) * 2048 + ((lane & 7) << 4);
  const char* bbase = (const char*)wt + (size_t)(col0 + wave * 8 + (lane >> 3)) * 2048 + ((lane & 7) << 4);
  char* aldst = As + wave * 1024;
  char* bldst = Bs + wave * 1024;

  for (int kk = 0; kk < 16; ++kk){
    const size_t koff = (size_t)kk << 7;
    #pragma unroll
    for (int c = 0; c < 4; ++c){
      gload_lds16(abase + (size_t)c * 65536 + koff, aldst + c * 4096);
      gload_lds16(bbase + (size_t)c * 65536 + koff, bldst + c * 4096);
    }
    __syncthreads();
    #pragma unroll
    for (int s = 0; s < 2; ++s){
      bf16x8 af[4], bfr[4];
      #pragma unroll
      for (int mt = 0; mt < 4; ++mt){
        int r = wr * 64 + mt * 16 + (lane & 15);
        int byte = (((lane >> 4) << 4) + (s << 6)) ^ ((r & 7) << 4);
        af[mt] = *(const bf16x8*)(As + r * 128 + byte);
      }
      #pragma unroll
      for (int nt = 0; nt < 4; ++nt){
        int cc = wc * 64 + nt * 16 + (lane & 15);
        int byte = (((lane >> 4) << 4) + (s << 6)) ^ ((cc & 7) << 4);
        bfr[nt] = *(const bf16x8*)(Bs + cc * 128 + byte);
      }
      #pragma unroll
      for (int mt = 0; mt < 4; ++mt)
        #pragma unroll
        for (int nt = 0; nt < 4; ++nt)
          acc[mt][nt] = __builtin_amdgcn_mfma_f32_16x16x32_bf16(af[mt], bfr[nt], acc[mt][nt], 0, 0, 0);
    }
    __syncthreads();
  }

  #pragma unroll
  for (int nt = 0; nt < 4; ++nt){
    int col = col0 + wc * 64 + nt * 16 + (lane & 15);
    float bia = bias[col];
    int h = col >> 6, d = col & 63;
    #pragma unroll
    for (int mt = 0; mt < 4; ++mt){
      #pragma unroll
      for (int r = 0; r < 4; ++r){
        int mrow = row0 + wr * 64 + mt * 16 + ((lane >> 4) << 2) + r;
        int b = mrow >> 11, n = mrow & 2047;
        float val = acc[mt][nt][r] + bia;
        if (v == 0){        // Q, scaled by 1/sqrt(D)=0.125 (exact in bf16)
          o0[((size_t)((b * 16 + h) * 2048 + n) << 6) + d] = f2bf(val * 0.125f);
        } else if (v == 1){ // K
          o1[((size_t)((b * 16 + h) * 2048 + n) << 6) + d] = f2bf(val);
        } else {            // V transposed: [b,h,d,n]
          o2[((size_t)((b * 16 + h) * 64 + d) << 11) + n] = f2bf(val);
        }
      }
    }
  }
}

// ---- causal flash attention, swapped-operand 32x32 MFMA, in-register softmax.
// One wave owns one 32-row q-tile for one head. S^T = K.Q^T (col = q = lane&31,
// row = kpos). Softmax state fully lane-local (2 shfl_xor(32) per tile).
// P->bf16 via v_cvt_pk_bf16_f32, redistributed via v_permlane32_swap_b32,
// PV computed as O^T = V^T.P^T so O shares the col=q layout. No LDS, no barriers.
template<int NKB, bool DIAG>
__device__ __forceinline__ void attn_tile(
    const unsigned short* __restrict__ kb, const unsigned short* __restrict__ vb,
    int kbase, int l31, int hi,
    const bf16x8* qf, float& m_, float& l_, f32x16& o0, f32x16& o1)
{
  // ---- K fragments (A-operand: row = kpos = lane&31, k-dim = 16i+8hi+j)
  bf16x8 kf0[4], kf1[4];
  #pragma unroll
  for (int i = 0; i < 4; ++i)
    kf0[i] = *(const bf16x8*)(kb + (size_t)(kbase + l31) * 64 + i * 16 + hi * 8);
  if (NKB == 2){
    #pragma unroll
    for (int i = 0; i < 4; ++i)
      kf1[i] = *(const bf16x8*)(kb + (size_t)(kbase + 32 + l31) * 64 + i * 16 + hi * 8);
  }
  // ---- QK^T (S^T): s[kpos][q]
  f32x16 s0 = {}, s1 = {};
  #pragma unroll
  for (int i = 0; i < 4; ++i)
    s0 = __builtin_amdgcn_mfma_f32_32x32x16_bf16(kf0[i], qf[i], s0, 0, 0, 0);
  if (NKB == 2){
    #pragma unroll
    for (int i = 0; i < 4; ++i)
      s1 = __builtin_amdgcn_mfma_f32_32x32x16_bf16(kf1[i], qf[i], s1, 0, 0, 0);
  }
  // ---- V^T fragments, issued early so L2 latency hides under softmax
  bf16x8 vf0[NKB * 2], vf1[NKB * 2];
  #pragma unroll
  for (int ks = 0; ks < NKB * 2; ++ks){
    vf0[ks] = *(const bf16x8*)(vb + (size_t)(l31) * 2048 + kbase + ks * 16 + hi * 8);
    vf1[ks] = *(const bf16x8*)(vb + (size_t)(32 + l31) * 2048 + kbase + ks * 16 + hi * 8);
  }
  // ---- causal mask on the diagonal 32-block (always the last kblk)
  if (DIAG){
    const int hi4 = hi * 4;
    #pragma unroll
    for (int r = 0; r < 16; ++r){
      int kloc = (r & 3) + 8 * (r >> 2) + hi4;
      if (NKB == 1){ if (kloc > l31) s0[r] = -1e38f; }
      else         { if (kloc > l31) s1[r] = -1e38f; }
    }
  }
  // ---- online softmax, lane-local + one cross-half exchange
  float mloc = -1e38f;
  #pragma unroll
  for (int r = 0; r < 16; ++r){
    mloc = fmaxf(mloc, s0[r]);
    if (NKB == 2) mloc = fmaxf(mloc, s1[r]);
  }
  mloc = fmaxf(mloc, __shfl_xor(mloc, 32));
  const float mnew = fmaxf(m_, mloc);
  const float mc = mnew * LOG2E;
  const float corr = __builtin_amdgcn_exp2f(__builtin_fmaf(m_, LOG2E, -mc));
  m_ = mnew;
  float rs = 0.f;
  #pragma unroll
  for (int r = 0; r < 16; ++r){
    s0[r] = __builtin_amdgcn_exp2f(__builtin_fmaf(s0[r], LOG2E, -mc));
    rs += s0[r];
    if (NKB == 2){
      s1[r] = __builtin_amdgcn_exp2f(__builtin_fmaf(s1[r], LOG2E, -mc));
      rs += s1[r];
    }
  }
  rs += __shfl_xor(rs, 32);
  l_ = l_ * corr + rs;
  o0 *= corr; o1 *= corr;
  // ---- pack P to bf16 pairs: u0[c],u1[c] cover k = 8c+4hi+{0,1},{2,3}
  unsigned int u0[NKB * 4], u1[NKB * 4];
  #pragma unroll
  for (int c = 0; c < NKB * 4; ++c){
    const int b4 = (c & 3) * 4;
    float p0 = (c < 4) ? s0[b4]     : s1[b4];
    float p1 = (c < 4) ? s0[b4 + 1] : s1[b4 + 1];
    float p2 = (c < 4) ? s0[b4 + 2] : s1[b4 + 2];
    float p3 = (c < 4) ? s0[b4 + 3] : s1[b4 + 3];
    unsigned int w0, w1;
    asm("v_cvt_pk_bf16_f32 %0, %1, %2" : "=v"(w0) : "v"(p0), "v"(p1));
    asm("v_cvt_pk_bf16_f32 %0, %1, %2" : "=v"(w1) : "v"(p2), "v"(p3));
    u0[c] = w0; u1[c] = w1;
  }
  // ---- PV: O^T += V^T . P^T  (B-operand frag built via permlane32_swap)
  #pragma unroll
  for (int ks = 0; ks < NKB * 2; ++ks){
    unsigned int a0 = u0[2 * ks], b0 = u0[2 * ks + 1];
    unsigned int a1 = u1[2 * ks], b1 = u1[2 * ks + 1];
    asm("v_permlane32_swap_b32 %0, %1" : "+v"(a0), "+v"(b0));
    asm("v_permlane32_swap_b32 %0, %1" : "+v"(a1), "+v"(b1));
    union { unsigned int u[4]; bf16x8 v; } pa;
    pa.u[0] = a0; pa.u[1] = a1; pa.u[2] = b0; pa.u[3] = b1;
    o0 = __builtin_amdgcn_mfma_f32_32x32x16_bf16(vf0[ks], pa.v, o0, 0, 0, 0);
    o1 = __builtin_amdgcn_mfma_f32_32x32x16_bf16(vf1[ks], pa.v, o1, 0, 0, 0);
  }
}

__global__ __launch_bounds__(256) void attn(
    const unsigned short* __restrict__ Qg, const unsigned short* __restrict__ Kg,
    const unsigned short* __restrict__ Vt, float* __restrict__ out){
  const int wave = threadIdx.x >> 6, lane = threadIdx.x & 63;
  const int head = blockIdx.x * 4 + wave;          // 16 groups x 4 waves = 64 heads
  const int t = 63 - (int)blockIdx.y;              // heavy q-tiles dispatch first
  const int l31 = lane & 31, hi = lane >> 5;
  const unsigned short* qb = Qg + ((size_t)head << 17);
  const unsigned short* kb = Kg + ((size_t)head << 17);
  const unsigned short* vb = Vt + ((size_t)head << 17);
  const int q0 = t * 32;

  bf16x8 qf[4];   // B-operand: col = q = lane&31, k-dim = 16i+8hi+j
  #pragma unroll
  for (int i = 0; i < 4; ++i)
    qf[i] = *(const bf16x8*)(qb + (size_t)(q0 + l31) * 64 + i * 16 + hi * 8);

  float m_ = -1e38f, l_ = 0.f;
  f32x16 o0 = {}, o1 = {};

  const int nfull = t >> 1;
  for (int i = 0; i < nfull; ++i)
    attn_tile<2, false>(kb, vb, i * 64, l31, hi, qf, m_, l_, o0, o1);
  if (t & 1)
    attn_tile<2, true>(kb, vb, nfull * 64, l31, hi, qf, m_, l_, o0, o1);
  else
    attn_tile<1, true>(kb, vb, nfull * 64, l31, hi, qf, m_, l_, o0, o1);

  // ---- epilogue: O^T[d][q] -> out[b, q, h*64+d], fp32
  const float inv = 1.f / l_;
  const int b = head >> 4, h = head & 15;
  float* op = out + ((size_t)(b * 2048 + q0 + l31) << 10) + h * 64 + hi * 4;
  #pragma unroll
  for (int c = 0; c < 4; ++c){
    *(float4*)(op + 8 * c) =
        make_float4(o0[4*c]*inv, o0[4*c+1]*inv, o0[4*c+2]*inv, o0[4*c+3]*inv);
    *(float4*)(op + 32 + 8 * c) =
        make_float4(o1[4*c]*inv, o1[4*c+1]*inv, o1[4*c+2]*inv, o1[4*c+3]*inv);
  }
}

extern "C" void kernel_launch(void* const* d_in, const int* in_sizes, int n_in,
                              void* d_out, int out_size, void* d_ws, size_t ws_size,
                              hipStream_t stream){
  const float* x  = (const float*)d_in[0];
  const float* Wq = (const float*)d_in[1];
  const float* bq = (const float*)d_in[2];
  const float* Wk = (const float*)d_in[3];
  const float* bk = (const float*)d_in[4];
  const float* Wv = (const float*)d_in[5];
  const float* bv = (const float*)d_in[6];
  float* out = (float*)d_out;
  char* ws = (char*)d_ws;
  // ws layout (bytes): xs 16MB | wtq/wtk/wtv 2MB each | Q 16MB | K 16MB | Vt 16MB = 70MB
  unsigned short* xs  = (unsigned short*)(ws);
  unsigned short* wtq = (unsigned short*)(ws + 16777216);
  unsigned short* wtk = (unsigned short*)(ws + 18874368);
  unsigned short* wtv = (unsigned short*)(ws + 20971520);
  unsigned short* Qg  = (unsigned short*)(ws + 23068672);
  unsigned short* Kg  = (unsigned short*)(ws + 39845888);
  unsigned short* Vt  = (unsigned short*)(ws + 56623104);

  cvt_x<<<4096, 256, 0, stream>>>(x, xs);
  cvt_w<<<dim3(512, 3), 256, 0, stream>>>(Wq, Wk, Wv, wtq, wtk, wtv);
  proj_gemm<<<dim3(64, 8, 3), 256, 0, stream>>>(xs, wtq, wtk, wtv, bq, bk, bv, Qg, Kg, Vt);
  attn<<<dim3(16, 64), 256, 0, stream>>>(Qg, Kg, Vt, out);
}

// Round 7
// 243.922 us; speedup vs baseline: 1.7053x; 1.2461x over previous
//
#include <hip/hip_runtime.h>

// B=4, N=2048, F=1024, H=16, D=64.  All dims hard-coded.
#define LOG2E 1.44269504088896340736f

typedef float f32x4 __attribute__((ext_vector_type(4)));
typedef float f32x16 __attribute__((ext_vector_type(16)));
typedef __bf16 bf16x8 __attribute__((ext_vector_type(8)));

__device__ __forceinline__ unsigned short f2bf(float f){
  unsigned int u = __builtin_bit_cast(unsigned int, f);
  u += 0x7fffu + ((u >> 16) & 1u);          // RNE
  return (unsigned short)(u >> 16);
}

__device__ __forceinline__ void gload_lds16(const void* g, void* l){
  __builtin_amdgcn_global_load_lds(
      (const __attribute__((address_space(1))) unsigned int*)g,
      (__attribute__((address_space(3))) unsigned int*)l, 16, 0, 0);
}

// ---- x (fp32 [8192][1024]) -> bf16, 128B-block swizzled: byte ^= ((row&7)<<4)
__global__ __launch_bounds__(256) void cvt_x(const float* __restrict__ x,
                                             unsigned short* __restrict__ xs){
  int t = blockIdx.x * 256 + threadIdx.x;   // 1,048,576 chunks of 8 elems
  int m = t >> 7, c = t & 127;
  const float4* p = (const float4*)(x + ((size_t)m << 10) + (c << 3));
  float4 f0 = p[0], f1 = p[1];
  unsigned int w0 = f2bf(f0.x) | ((unsigned int)f2bf(f0.y) << 16);
  unsigned int w1 = f2bf(f0.z) | ((unsigned int)f2bf(f0.w) << 16);
  unsigned int w2 = f2bf(f1.x) | ((unsigned int)f2bf(f1.y) << 16);
  unsigned int w3 = f2bf(f1.z) | ((unsigned int)f2bf(f1.w) << 16);
  int byte = (c << 4) ^ ((m & 7) << 4);
  *(uint4*)((char*)xs + ((size_t)m << 11) + byte) = make_uint4(w0, w1, w2, w3);
}

// ---- W (fp32 [1024k][1024n]) -> bf16 transposed Wt[n][k], same swizzle by n
__global__ __launch_bounds__(256) void cvt_w(const float* __restrict__ Wq,
                                             const float* __restrict__ Wk,
                                             const float* __restrict__ Wv,
                                             unsigned short* __restrict__ wtq,
                                             unsigned short* __restrict__ wtk,
                                             unsigned short* __restrict__ wtv){
  int t = blockIdx.x * 256 + threadIdx.x;   // 131072 per matrix
  int n = t & 1023, c = t >> 10;            // c = k-chunk (8 k's)
  const float* W = blockIdx.y == 0 ? Wq : blockIdx.y == 1 ? Wk : Wv;
  unsigned short* o = blockIdx.y == 0 ? wtq : blockIdx.y == 1 ? wtk : wtv;
  unsigned int w[4];
  #pragma unroll
  for (int i = 0; i < 4; ++i){
    float a = W[(size_t)(c * 8 + 2 * i) * 1024 + n];
    float b = W[(size_t)(c * 8 + 2 * i + 1) * 1024 + n];
    w[i] = f2bf(a) | ((unsigned int)f2bf(b) << 16);
  }
  int byte = (c << 4) ^ ((n & 7) << 4);
  *(uint4*)((char*)o + ((size_t)n << 11) + byte) = make_uint4(w[0], w[1], w[2], w[3]);
}

// ---- projection GEMM: C[8192][1024] = xs @ Wt^T (+bias). z picks Q/K/V.
// 128x128 tile, BK=64, 4 waves, global_load_lds(16B), swizzled ds_read_b128.
// Q: scaled by 0.125, layout [b,h,n,d]. K: [b,h,n,d]. V: transposed [b,h,d,n].
__global__ __launch_bounds__(256) void proj_gemm(
    const unsigned short* __restrict__ xs,
    const unsigned short* __restrict__ wt0, const unsigned short* __restrict__ wt1,
    const unsigned short* __restrict__ wt2,
    const float* __restrict__ b0, const float* __restrict__ b1, const float* __restrict__ b2,
    unsigned short* __restrict__ o0, unsigned short* __restrict__ o1,
    unsigned short* __restrict__ o2){
  __shared__ char As[16384];
  __shared__ char Bs[16384];
  const int v = blockIdx.z;
  const unsigned short* wt = v == 0 ? wt0 : v == 1 ? wt1 : wt2;
  const float* bias = v == 0 ? b0 : v == 1 ? b1 : b2;
  const int row0 = blockIdx.x << 7;
  const int col0 = blockIdx.y << 7;
  const int tid = threadIdx.x;
  const int wave = tid >> 6, lane = tid & 63;
  const int wr = wave >> 1, wc = wave & 1;
  f32x4 acc[4][4] = {};

  const char* abase = (const char*)xs + (size_t)(row0 + wave * 8 + (lane >> 3)) * 2048 + ((lane & 7) << 4);
  const char* bbase = (const char*)wt + (size_t)(col0 + wave * 8 + (lane >> 3)) * 2048 + ((lane & 7) << 4);
  char* aldst = As + wave * 1024;
  char* bldst = Bs + wave * 1024;

  for (int kk = 0; kk < 16; ++kk){
    const size_t koff = (size_t)kk << 7;
    #pragma unroll
    for (int c = 0; c < 4; ++c){
      gload_lds16(abase + (size_t)c * 65536 + koff, aldst + c * 4096);
      gload_lds16(bbase + (size_t)c * 65536 + koff, bldst + c * 4096);
    }
    __syncthreads();
    #pragma unroll
    for (int s = 0; s < 2; ++s){
      bf16x8 af[4], bfr[4];
      #pragma unroll
      for (int mt = 0; mt < 4; ++mt){
        int r = wr * 64 + mt * 16 + (lane & 15);
        int byte = (((lane >> 4) << 4) + (s << 6)) ^ ((r & 7) << 4);
        af[mt] = *(const bf16x8*)(As + r * 128 + byte);
      }
      #pragma unroll
      for (int nt = 0; nt < 4; ++nt){
        int cc = wc * 64 + nt * 16 + (lane & 15);
        int byte = (((lane >> 4) << 4) + (s << 6)) ^ ((cc & 7) << 4);
        bfr[nt] = *(const bf16x8*)(Bs + cc * 128 + byte);
      }
      #pragma unroll
      for (int mt = 0; mt < 4; ++mt)
        #pragma unroll
        for (int nt = 0; nt < 4; ++nt)
          acc[mt][nt] = __builtin_amdgcn_mfma_f32_16x16x32_bf16(af[mt], bfr[nt], acc[mt][nt], 0, 0, 0);
    }
    __syncthreads();
  }

  #pragma unroll
  for (int nt = 0; nt < 4; ++nt){
    int col = col0 + wc * 64 + nt * 16 + (lane & 15);
    float bia = bias[col];
    int h = col >> 6, d = col & 63;
    #pragma unroll
    for (int mt = 0; mt < 4; ++mt){
      #pragma unroll
      for (int r = 0; r < 4; ++r){
        int mrow = row0 + wr * 64 + mt * 16 + ((lane >> 4) << 2) + r;
        int b = mrow >> 11, n = mrow & 2047;
        float val = acc[mt][nt][r] + bia;
        if (v == 0){        // Q, scaled by 1/sqrt(D)=0.125 (exact in bf16)
          o0[((size_t)((b * 16 + h) * 2048 + n) << 6) + d] = f2bf(val * 0.125f);
        } else if (v == 1){ // K
          o1[((size_t)((b * 16 + h) * 2048 + n) << 6) + d] = f2bf(val);
        } else {            // V transposed: [b,h,d,n]
          o2[((size_t)((b * 16 + h) * 64 + d) << 11) + n] = f2bf(val);
        }
      }
    }
  }
}

// ---- causal flash attention, LDS-staged K/V shared by 4 waves of one head.
// Block = (head, 4 consecutive q-tiles). Per-wave math identical to the verified
// swapped-operand version: S^T = K.Q^T, lane-local online softmax (2 shfl/tile),
// P->bf16 via v_cvt_pk_bf16_f32 + v_permlane32_swap_b32, O^T = V^T.P^T.
// K/V tiles staged via global_load_lds with XOR-swizzled SOURCE address
// (linear LDS dest, rule: source perm == read perm), double-buffered.
template<int NKB, bool DIAG>
__device__ __forceinline__ void attn_tile_lds(
    const char* __restrict__ Kl, const char* __restrict__ Vl,
    int l31, int hi, int sw,
    const bf16x8* qf, float& m_, float& l_, f32x16& o0, f32x16& o1)
{
  // ---- K fragments from LDS (row = kpos, chunk = 2i+hi, swizzled by row&7)
  bf16x8 kf0[4], kf1[4];
  #pragma unroll
  for (int i = 0; i < 4; ++i)
    kf0[i] = *(const bf16x8*)(Kl + l31 * 128 + ((((2 * i + hi) << 4)) ^ sw));
  if (NKB == 2){
    #pragma unroll
    for (int i = 0; i < 4; ++i)
      kf1[i] = *(const bf16x8*)(Kl + (32 + l31) * 128 + ((((2 * i + hi) << 4)) ^ sw));
  }
  // ---- QK^T (S^T): s[kpos][q]
  f32x16 s0 = {}, s1 = {};
  #pragma unroll
  for (int i = 0; i < 4; ++i)
    s0 = __builtin_amdgcn_mfma_f32_32x32x16_bf16(kf0[i], qf[i], s0, 0, 0, 0);
  if (NKB == 2){
    #pragma unroll
    for (int i = 0; i < 4; ++i)
      s1 = __builtin_amdgcn_mfma_f32_32x32x16_bf16(kf1[i], qf[i], s1, 0, 0, 0);
  }
  // ---- V^T fragments from LDS (row = d, chunk = 2ks+hi)
  bf16x8 vf0[NKB * 2], vf1[NKB * 2];
  #pragma unroll
  for (int ks = 0; ks < NKB * 2; ++ks){
    vf0[ks] = *(const bf16x8*)(Vl + l31 * 128 + ((((2 * ks + hi) << 4)) ^ sw));
    vf1[ks] = *(const bf16x8*)(Vl + (32 + l31) * 128 + ((((2 * ks + hi) << 4)) ^ sw));
  }
  // ---- causal mask on the diagonal 32-block (always the last kblk)
  if (DIAG){
    const int hi4 = hi * 4;
    #pragma unroll
    for (int r = 0; r < 16; ++r){
      int kloc = (r & 3) + 8 * (r >> 2) + hi4;
      if (NKB == 1){ if (kloc > l31) s0[r] = -1e38f; }
      else         { if (kloc > l31) s1[r] = -1e38f; }
    }
  }
  // ---- online softmax, lane-local + one cross-half exchange
  float mloc = -1e38f;
  #pragma unroll
  for (int r = 0; r < 16; ++r){
    mloc = fmaxf(mloc, s0[r]);
    if (NKB == 2) mloc = fmaxf(mloc, s1[r]);
  }
  mloc = fmaxf(mloc, __shfl_xor(mloc, 32));
  const float mnew = fmaxf(m_, mloc);
  const float mc = mnew * LOG2E;
  const float corr = __builtin_amdgcn_exp2f(__builtin_fmaf(m_, LOG2E, -mc));
  m_ = mnew;
  float rs = 0.f;
  #pragma unroll
  for (int r = 0; r < 16; ++r){
    s0[r] = __builtin_amdgcn_exp2f(__builtin_fmaf(s0[r], LOG2E, -mc));
    rs += s0[r];
    if (NKB == 2){
      s1[r] = __builtin_amdgcn_exp2f(__builtin_fmaf(s1[r], LOG2E, -mc));
      rs += s1[r];
    }
  }
  rs += __shfl_xor(rs, 32);
  l_ = l_ * corr + rs;
  o0 *= corr; o1 *= corr;
  // ---- pack P to bf16 pairs: u0[c],u1[c] cover k = 8c+4hi+{0,1},{2,3}
  unsigned int u0[NKB * 4], u1[NKB * 4];
  #pragma unroll
  for (int c = 0; c < NKB * 4; ++c){
    const int b4 = (c & 3) * 4;
    float p0 = (c < 4) ? s0[b4]     : s1[b4];
    float p1 = (c < 4) ? s0[b4 + 1] : s1[b4 + 1];
    float p2 = (c < 4) ? s0[b4 + 2] : s1[b4 + 2];
    float p3 = (c < 4) ? s0[b4 + 3] : s1[b4 + 3];
    unsigned int w0, w1;
    asm("v_cvt_pk_bf16_f32 %0, %1, %2" : "=v"(w0) : "v"(p0), "v"(p1));
    asm("v_cvt_pk_bf16_f32 %0, %1, %2" : "=v"(w1) : "v"(p2), "v"(p3));
    u0[c] = w0; u1[c] = w1;
  }
  // ---- PV: O^T += V^T . P^T  (B-operand frag built via permlane32_swap)
  #pragma unroll
  for (int ks = 0; ks < NKB * 2; ++ks){
    unsigned int a0 = u0[2 * ks], b0 = u0[2 * ks + 1];
    unsigned int a1 = u1[2 * ks], b1 = u1[2 * ks + 1];
    asm("v_permlane32_swap_b32 %0, %1" : "+v"(a0), "+v"(b0));
    asm("v_permlane32_swap_b32 %0, %1" : "+v"(a1), "+v"(b1));
    union { unsigned int u[4]; bf16x8 v; } pa;
    pa.u[0] = a0; pa.u[1] = a1; pa.u[2] = b0; pa.u[3] = b1;
    o0 = __builtin_amdgcn_mfma_f32_32x32x16_bf16(vf0[ks], pa.v, o0, 0, 0, 0);
    o1 = __builtin_amdgcn_mfma_f32_32x32x16_bf16(vf1[ks], pa.v, o1, 0, 0, 0);
  }
}

__global__ __launch_bounds__(256) void attn(
    const unsigned short* __restrict__ Qg, const unsigned short* __restrict__ Kg,
    const unsigned short* __restrict__ Vt, float* __restrict__ out){
  // XCD-affinity mapping (assumes consecutive bids round-robin the 8 XCDs):
  // 8 heads per XCD -> per-XCD K+V working set 4 MB = L2 size.
  const int bid = blockIdx.x;                // 1024 blocks
  const int xcd = bid & 7, slot = bid >> 3;  // 128 slots per XCD
  const int head = xcd * 8 + (slot & 7);
  const int u = 15 - (slot >> 3);            // q-tile group, heavy-first
  const int wave = threadIdx.x >> 6, lane = threadIdx.x & 63;
  const int l31 = lane & 31, hi = lane >> 5;
  const int sw = (l31 & 7) << 4;             // read-side swizzle
  const int t = 4 * u + wave;                // this wave's q-tile
  const int q0 = t * 32;
  const int nfull = t >> 1;                  // full 64-wide KV tiles
  const bool odd = t & 1;
  const int ktmax = 2 * u + 1;               // last kt index for the block

  const unsigned short* qb = Qg + ((size_t)head << 17);
  const char* kbg = (const char*)(Kg + ((size_t)head << 17));
  const char* vbg = (const char*)(Vt + ((size_t)head << 17));

  __shared__ char Kl[2][8192];
  __shared__ char Vl[2][8192];

  bf16x8 qf[4];   // B-operand: col = q = lane&31, k-dim = 16i+8hi+j
  #pragma unroll
  for (int i = 0; i < 4; ++i)
    qf[i] = *(const bf16x8*)(qb + (size_t)(q0 + l31) * 64 + i * 16 + hi * 8);

  // staging: linear LDS dest, XOR-swizzled global source (perm == read perm).
  // per wave+round: 8 rows x 128B; lane covers row rows8+(lane>>3), chunk lane&7.
  const int csw = (((lane & 7) ^ (lane >> 3)) << 4) ;
  const int lrow = lane >> 3;
  #define STAGE(buf, kt) do {                                                   \
    _Pragma("unroll")                                                           \
    for (int r_ = 0; r_ < 2; ++r_){                                             \
      int rows8_ = (r_ * 4 + wave) * 8;                                         \
      int row_ = rows8_ + lrow;                                                 \
      gload_lds16(kbg + (size_t)((kt) * 64 + row_) * 128 + csw,                 \
                  Kl[buf] + (r_ * 4 + wave) * 1024);                            \
      gload_lds16(vbg + (size_t)row_ * 4096 + (size_t)(kt) * 128 + csw,         \
                  Vl[buf] + (r_ * 4 + wave) * 1024);                            \
    }                                                                           \
  } while (0)

  float m_ = -1e38f, l_ = 0.f;
  f32x16 o0 = {}, o1 = {};

  STAGE(0, 0);
  __syncthreads();
  int cur = 0;
  for (int kt = 0; kt <= ktmax; ++kt){
    if (kt < ktmax) STAGE(cur ^ 1, kt + 1);
    if (kt < nfull){
      attn_tile_lds<2, false>(Kl[cur], Vl[cur], l31, hi, sw, qf, m_, l_, o0, o1);
    } else if (kt == nfull){
      if (odd) attn_tile_lds<2, true>(Kl[cur], Vl[cur], l31, hi, sw, qf, m_, l_, o0, o1);
      else     attn_tile_lds<1, true>(Kl[cur], Vl[cur], l31, hi, sw, qf, m_, l_, o0, o1);
    }
    __syncthreads();
    cur ^= 1;
  }
  #undef STAGE

  // ---- epilogue: O^T[d][q] -> out[b, q, h*64+d], fp32
  const float inv = 1.f / l_;
  const int b = head >> 4, h = head & 15;
  float* op = out + ((size_t)(b * 2048 + q0 + l31) << 10) + h * 64 + hi * 4;
  #pragma unroll
  for (int c = 0; c < 4; ++c){
    *(float4*)(op + 8 * c) =
        make_float4(o0[4*c]*inv, o0[4*c+1]*inv, o0[4*c+2]*inv, o0[4*c+3]*inv);
    *(float4*)(op + 32 + 8 * c) =
        make_float4(o1[4*c]*inv, o1[4*c+1]*inv, o1[4*c+2]*inv, o1[4*c+3]*inv);
  }
}

extern "C" void kernel_launch(void* const* d_in, const int* in_sizes, int n_in,
                              void* d_out, int out_size, void* d_ws, size_t ws_size,
                              hipStream_t stream){
  const float* x  = (const float*)d_in[0];
  const float* Wq = (const float*)d_in[1];
  const float* bq = (const float*)d_in[2];
  const float* Wk = (const float*)d_in[3];
  const float* bk = (const float*)d_in[4];
  const float* Wv = (const float*)d_in[5];
  const float* bv = (const float*)d_in[6];
  float* out = (float*)d_out;
  char* ws = (char*)d_ws;
  // ws layout (bytes): xs 16MB | wtq/wtk/wtv 2MB each | Q 16MB | K 16MB | Vt 16MB = 70MB
  unsigned short* xs  = (unsigned short*)(ws);
  unsigned short* wtq = (unsigned short*)(ws + 16777216);
  unsigned short* wtk = (unsigned short*)(ws + 18874368);
  unsigned short* wtv = (unsigned short*)(ws + 20971520);
  unsigned short* Qg  = (unsigned short*)(ws + 23068672);
  unsigned short* Kg  = (unsigned short*)(ws + 39845888);
  unsigned short* Vt  = (unsigned short*)(ws + 56623104);

  cvt_x<<<4096, 256, 0, stream>>>(x, xs);
  cvt_w<<<dim3(512, 3), 256, 0, stream>>>(Wq, Wk, Wv, wtq, wtk, wtv);
  proj_gemm<<<dim3(64, 8, 3), 256, 0, stream>>>(xs, wtq, wtk, wtv, bq, bk, bv, Qg, Kg, Vt);
  attn<<<1024, 256, 0, stream>>>(Qg, Kg, Vt, out);
}

// Round 9
// 240.964 us; speedup vs baseline: 1.7262x; 1.0123x over previous
//
#include <hip/hip_runtime.h>

// B=4, N=2048, F=1024, H=16, D=64.  All dims hard-coded.
#define LOG2E 1.44269504088896340736f

typedef float f32x4 __attribute__((ext_vector_type(4)));
typedef float f32x16 __attribute__((ext_vector_type(16)));
typedef __bf16 bf16x8 __attribute__((ext_vector_type(8)));

__device__ __forceinline__ unsigned short f2bf(float f){
  unsigned int u = __builtin_bit_cast(unsigned int, f);
  u += 0x7fffu + ((u >> 16) & 1u);          // RNE
  return (unsigned short)(u >> 16);
}

__device__ __forceinline__ void gload_lds16(const void* g, void* l){
  __builtin_amdgcn_global_load_lds(
      (const __attribute__((address_space(1))) unsigned int*)g,
      (__attribute__((address_space(3))) unsigned int*)l, 16, 0, 0);
}

// ---- x (fp32 [8192][1024]) -> bf16, 128B-block swizzled: byte ^= ((row&7)<<4)
__global__ __launch_bounds__(256) void cvt_x(const float* __restrict__ x,
                                             unsigned short* __restrict__ xs){
  int t = blockIdx.x * 256 + threadIdx.x;   // 1,048,576 chunks of 8 elems
  int m = t >> 7, c = t & 127;
  const float4* p = (const float4*)(x + ((size_t)m << 10) + (c << 3));
  float4 f0 = p[0], f1 = p[1];
  unsigned int w0 = f2bf(f0.x) | ((unsigned int)f2bf(f0.y) << 16);
  unsigned int w1 = f2bf(f0.z) | ((unsigned int)f2bf(f0.w) << 16);
  unsigned int w2 = f2bf(f1.x) | ((unsigned int)f2bf(f1.y) << 16);
  unsigned int w3 = f2bf(f1.z) | ((unsigned int)f2bf(f1.w) << 16);
  int byte = (c << 4) ^ ((m & 7) << 4);
  *(uint4*)((char*)xs + ((size_t)m << 11) + byte) = make_uint4(w0, w1, w2, w3);
}

// ---- W (fp32 [1024k][1024n]) -> bf16 transposed Wt[n][k], same swizzle by n
__global__ __launch_bounds__(256) void cvt_w(const float* __restrict__ Wq,
                                             const float* __restrict__ Wk,
                                             const float* __restrict__ Wv,
                                             unsigned short* __restrict__ wtq,
                                             unsigned short* __restrict__ wtk,
                                             unsigned short* __restrict__ wtv){
  int t = blockIdx.x * 256 + threadIdx.x;   // 131072 per matrix
  int n = t & 1023, c = t >> 10;            // c = k-chunk (8 k's)
  const float* W = blockIdx.y == 0 ? Wq : blockIdx.y == 1 ? Wk : Wv;
  unsigned short* o = blockIdx.y == 0 ? wtq : blockIdx.y == 1 ? wtk : wtv;
  unsigned int w[4];
  #pragma unroll
  for (int i = 0; i < 4; ++i){
    float a = W[(size_t)(c * 8 + 2 * i) * 1024 + n];
    float b = W[(size_t)(c * 8 + 2 * i + 1) * 1024 + n];
    w[i] = f2bf(a) | ((unsigned int)f2bf(b) << 16);
  }
  int byte = (c << 4) ^ ((n & 7) << 4);
  *(uint4*)((char*)o + ((size_t)n << 11) + byte) = make_uint4(w[0], w[1], w[2], w[3]);
}

// ---- projection GEMM: C[8192][1024] = xs @ Wt^T (+bias). z picks Q/K/V.
// 128x128 tile, BK=64, 4 waves. 2-PHASE PREFETCH DOUBLE-BUFFER (T3-minimum):
// STAGE(next) issued BEFORE compute(cur); ONE __syncthreads per K-step, so the
// next tile's global_load_lds fly under the current tile's MFMA+ds_read.
// Q: scaled by 0.125, layout [b,h,n,d]. K: [b,h,n,d]. V: transposed [b,h,d,n].
__global__ __launch_bounds__(256) void proj_gemm(
    const unsigned short* __restrict__ xs,
    const unsigned short* __restrict__ wt0, const unsigned short* __restrict__ wt1,
    const unsigned short* __restrict__ wt2,
    const float* __restrict__ b0, const float* __restrict__ b1, const float* __restrict__ b2,
    unsigned short* __restrict__ o0, unsigned short* __restrict__ o1,
    unsigned short* __restrict__ o2){
  __shared__ char As[2][16384];
  __shared__ char Bs[2][16384];
  const int v = blockIdx.z;
  const unsigned short* wt = v == 0 ? wt0 : v == 1 ? wt1 : wt2;
  const float* bias = v == 0 ? b0 : v == 1 ? b1 : b2;
  const int row0 = blockIdx.x << 7;
  const int col0 = blockIdx.y << 7;
  const int tid = threadIdx.x;
  const int wave = tid >> 6, lane = tid & 63;
  const int wr = wave >> 1, wc = wave & 1;
  f32x4 acc[4][4] = {};

  const char* abase = (const char*)xs + (size_t)(row0 + wave * 8 + (lane >> 3)) * 2048 + ((lane & 7) << 4);
  const char* bbase = (const char*)wt + (size_t)(col0 + wave * 8 + (lane >> 3)) * 2048 + ((lane & 7) << 4);
  const int ldoff = wave * 1024;

  #define PSTAGE(buf, kk) do {                                                  \
    const size_t koff_ = (size_t)(kk) << 7;                                     \
    _Pragma("unroll")                                                           \
    for (int c_ = 0; c_ < 4; ++c_){                                             \
      gload_lds16(abase + (size_t)c_ * 65536 + koff_, As[buf] + ldoff + c_ * 4096); \
      gload_lds16(bbase + (size_t)c_ * 65536 + koff_, Bs[buf] + ldoff + c_ * 4096); \
    }                                                                           \
  } while (0)

  PSTAGE(0, 0);
  __syncthreads();
  int cur = 0;
  for (int kk = 0; kk < 16; ++kk){
    if (kk < 15) PSTAGE(cur ^ 1, kk + 1);   // prefetch flies under compute
    #pragma unroll
    for (int s = 0; s < 2; ++s){
      bf16x8 af[4], bfr[4];
      #pragma unroll
      for (int mt = 0; mt < 4; ++mt){
        int r = wr * 64 + mt * 16 + (lane & 15);
        int byte = (((lane >> 4) << 4) + (s << 6)) ^ ((r & 7) << 4);
        af[mt] = *(const bf16x8*)(As[cur] + r * 128 + byte);
      }
      #pragma unroll
      for (int nt = 0; nt < 4; ++nt){
        int cc = wc * 64 + nt * 16 + (lane & 15);
        int byte = (((lane >> 4) << 4) + (s << 6)) ^ ((cc & 7) << 4);
        bfr[nt] = *(const bf16x8*)(Bs[cur] + cc * 128 + byte);
      }
      #pragma unroll
      for (int mt = 0; mt < 4; ++mt)
        #pragma unroll
        for (int nt = 0; nt < 4; ++nt)
          acc[mt][nt] = __builtin_amdgcn_mfma_f32_16x16x32_bf16(af[mt], bfr[nt], acc[mt][nt], 0, 0, 0);
    }
    __syncthreads();   // drains prefetch (own-wave vmcnt) + guards buf reuse
    cur ^= 1;
  }
  #undef PSTAGE

  #pragma unroll
  for (int nt = 0; nt < 4; ++nt){
    int col = col0 + wc * 64 + nt * 16 + (lane & 15);
    float bia = bias[col];
    int h = col >> 6, d = col & 63;
    #pragma unroll
    for (int mt = 0; mt < 4; ++mt){
      #pragma unroll
      for (int r = 0; r < 4; ++r){
        int mrow = row0 + wr * 64 + mt * 16 + ((lane >> 4) << 2) + r;
        int b = mrow >> 11, n = mrow & 2047;
        float val = acc[mt][nt][r] + bia;
        if (v == 0){        // Q, scaled by 1/sqrt(D)=0.125 (exact in bf16)
          o0[((size_t)((b * 16 + h) * 2048 + n) << 6) + d] = f2bf(val * 0.125f);
        } else if (v == 1){ // K
          o1[((size_t)((b * 16 + h) * 2048 + n) << 6) + d] = f2bf(val);
        } else {            // V transposed: [b,h,d,n]
          o2[((size_t)((b * 16 + h) * 64 + d) << 11) + n] = f2bf(val);
        }
      }
    }
  }
}

// ---- causal flash attention, LDS-staged K/V shared by 4 waves of one head.
// Block = (head, 4 consecutive q-tiles). Per-wave math identical to the verified
// swapped-operand version: S^T = K.Q^T, lane-local online softmax (2 shfl/tile),
// P->bf16 via v_cvt_pk_bf16_f32 + v_permlane32_swap_b32, O^T = V^T.P^T.
// K/V tiles staged via global_load_lds with XOR-swizzled SOURCE address
// (linear LDS dest, rule: source perm == read perm), double-buffered.
template<int NKB, bool DIAG>
__device__ __forceinline__ void attn_tile_lds(
    const char* __restrict__ Kl, const char* __restrict__ Vl,
    int l31, int hi, int sw,
    const bf16x8* qf, float& m_, float& l_, f32x16& o0, f32x16& o1)
{
  // ---- K fragments from LDS (row = kpos, chunk = 2i+hi, swizzled by row&7)
  bf16x8 kf0[4], kf1[4];
  #pragma unroll
  for (int i = 0; i < 4; ++i)
    kf0[i] = *(const bf16x8*)(Kl + l31 * 128 + ((((2 * i + hi) << 4)) ^ sw));
  if (NKB == 2){
    #pragma unroll
    for (int i = 0; i < 4; ++i)
      kf1[i] = *(const bf16x8*)(Kl + (32 + l31) * 128 + ((((2 * i + hi) << 4)) ^ sw));
  }
  // ---- QK^T (S^T): s[kpos][q]
  f32x16 s0 = {}, s1 = {};
  #pragma unroll
  for (int i = 0; i < 4; ++i)
    s0 = __builtin_amdgcn_mfma_f32_32x32x16_bf16(kf0[i], qf[i], s0, 0, 0, 0);
  if (NKB == 2){
    #pragma unroll
    for (int i = 0; i < 4; ++i)
      s1 = __builtin_amdgcn_mfma_f32_32x32x16_bf16(kf1[i], qf[i], s1, 0, 0, 0);
  }
  // ---- V^T fragments from LDS (row = d, chunk = 2ks+hi)
  bf16x8 vf0[NKB * 2], vf1[NKB * 2];
  #pragma unroll
  for (int ks = 0; ks < NKB * 2; ++ks){
    vf0[ks] = *(const bf16x8*)(Vl + l31 * 128 + ((((2 * ks + hi) << 4)) ^ sw));
    vf1[ks] = *(const bf16x8*)(Vl + (32 + l31) * 128 + ((((2 * ks + hi) << 4)) ^ sw));
  }
  // ---- causal mask on the diagonal 32-block (always the last kblk)
  if (DIAG){
    const int hi4 = hi * 4;
    #pragma unroll
    for (int r = 0; r < 16; ++r){
      int kloc = (r & 3) + 8 * (r >> 2) + hi4;
      if (NKB == 1){ if (kloc > l31) s0[r] = -1e38f; }
      else         { if (kloc > l31) s1[r] = -1e38f; }
    }
  }
  // ---- online softmax, lane-local + one cross-half exchange
  float mloc = -1e38f;
  #pragma unroll
  for (int r = 0; r < 16; ++r){
    mloc = fmaxf(mloc, s0[r]);
    if (NKB == 2) mloc = fmaxf(mloc, s1[r]);
  }
  mloc = fmaxf(mloc, __shfl_xor(mloc, 32));
  const float mnew = fmaxf(m_, mloc);
  const float mc = mnew * LOG2E;
  const float corr = __builtin_amdgcn_exp2f(__builtin_fmaf(m_, LOG2E, -mc));
  m_ = mnew;
  float rs = 0.f;
  #pragma unroll
  for (int r = 0; r < 16; ++r){
    s0[r] = __builtin_amdgcn_exp2f(__builtin_fmaf(s0[r], LOG2E, -mc));
    rs += s0[r];
    if (NKB == 2){
      s1[r] = __builtin_amdgcn_exp2f(__builtin_fmaf(s1[r], LOG2E, -mc));
      rs += s1[r];
    }
  }
  rs += __shfl_xor(rs, 32);
  l_ = l_ * corr + rs;
  o0 *= corr; o1 *= corr;
  // ---- pack P to bf16 pairs: u0[c],u1[c] cover k = 8c+4hi+{0,1},{2,3}
  unsigned int u0[NKB * 4], u1[NKB * 4];
  #pragma unroll
  for (int c = 0; c < NKB * 4; ++c){
    const int b4 = (c & 3) * 4;
    float p0 = (c < 4) ? s0[b4]     : s1[b4];
    float p1 = (c < 4) ? s0[b4 + 1] : s1[b4 + 1];
    float p2 = (c < 4) ? s0[b4 + 2] : s1[b4 + 2];
    float p3 = (c < 4) ? s0[b4 + 3] : s1[b4 + 3];
    unsigned int w0, w1;
    asm("v_cvt_pk_bf16_f32 %0, %1, %2" : "=v"(w0) : "v"(p0), "v"(p1));
    asm("v_cvt_pk_bf16_f32 %0, %1, %2" : "=v"(w1) : "v"(p2), "v"(p3));
    u0[c] = w0; u1[c] = w1;
  }
  // ---- PV: O^T += V^T . P^T  (B-operand frag built via permlane32_swap)
  #pragma unroll
  for (int ks = 0; ks < NKB * 2; ++ks){
    unsigned int a0 = u0[2 * ks], b0 = u0[2 * ks + 1];
    unsigned int a1 = u1[2 * ks], b1 = u1[2 * ks + 1];
    asm("v_permlane32_swap_b32 %0, %1" : "+v"(a0), "+v"(b0));
    asm("v_permlane32_swap_b32 %0, %1" : "+v"(a1), "+v"(b1));
    union { unsigned int u[4]; bf16x8 v; } pa;
    pa.u[0] = a0; pa.u[1] = a1; pa.u[2] = b0; pa.u[3] = b1;
    o0 = __builtin_amdgcn_mfma_f32_32x32x16_bf16(vf0[ks], pa.v, o0, 0, 0, 0);
    o1 = __builtin_amdgcn_mfma_f32_32x32x16_bf16(vf1[ks], pa.v, o1, 0, 0, 0);
  }
}

__global__ __launch_bounds__(256) void attn(
    const unsigned short* __restrict__ Qg, const unsigned short* __restrict__ Kg,
    const unsigned short* __restrict__ Vt, float* __restrict__ out){
  // XCD-affinity mapping (assumes consecutive bids round-robin the 8 XCDs):
  // 8 heads per XCD -> per-XCD K+V working set 4 MB = L2 size.
  const int bid = blockIdx.x;                // 1024 blocks
  const int xcd = bid & 7, slot = bid >> 3;  // 128 slots per XCD
  const int head = xcd * 8 + (slot & 7);
  const int u = 15 - (slot >> 3);            // q-tile group, heavy-first
  const int wave = threadIdx.x >> 6, lane = threadIdx.x & 63;
  const int l31 = lane & 31, hi = lane >> 5;
  const int sw = (l31 & 7) << 4;             // read-side swizzle
  const int t = 4 * u + wave;                // this wave's q-tile
  const int q0 = t * 32;
  const int nfull = t >> 1;                  // full 64-wide KV tiles
  const bool odd = t & 1;
  const int ktmax = 2 * u + 1;               // last kt index for the block

  const unsigned short* qb = Qg + ((size_t)head << 17);
  const char* kbg = (const char*)(Kg + ((size_t)head << 17));
  const char* vbg = (const char*)(Vt + ((size_t)head << 17));

  __shared__ char Kl[2][8192];
  __shared__ char Vl[2][8192];

  bf16x8 qf[4];   // B-operand: col = q = lane&31, k-dim = 16i+8hi+j
  #pragma unroll
  for (int i = 0; i < 4; ++i)
    qf[i] = *(const bf16x8*)(qb + (size_t)(q0 + l31) * 64 + i * 16 + hi * 8);

  // staging: linear LDS dest, XOR-swizzled global source (perm == read perm).
  // per wave+round: 8 rows x 128B; lane covers row rows8+(lane>>3), chunk lane&7.
  const int csw = (((lane & 7) ^ (lane >> 3)) << 4) ;
  const int lrow = lane >> 3;
  #define STAGE(buf, kt) do {                                                   \
    _Pragma("unroll")                                                           \
    for (int r_ = 0; r_ < 2; ++r_){                                             \
      int rows8_ = (r_ * 4 + wave) * 8;                                         \
      int row_ = rows8_ + lrow;                                                 \
      gload_lds16(kbg + (size_t)((kt) * 64 + row_) * 128 + csw,                 \
                  Kl[buf] + (r_ * 4 + wave) * 1024);                            \
      gload_lds16(vbg + (size_t)row_ * 4096 + (size_t)(kt) * 128 + csw,         \
                  Vl[buf] + (r_ * 4 + wave) * 1024);                            \
    }                                                                           \
  } while (0)

  float m_ = -1e38f, l_ = 0.f;
  f32x16 o0 = {}, o1 = {};

  STAGE(0, 0);
  __syncthreads();
  int cur = 0;
  for (int kt = 0; kt <= ktmax; ++kt){
    if (kt < ktmax) STAGE(cur ^ 1, kt + 1);
    if (kt < nfull){
      attn_tile_lds<2, false>(Kl[cur], Vl[cur], l31, hi, sw, qf, m_, l_, o0, o1);
    } else if (kt == nfull){
      if (odd) attn_tile_lds<2, true>(Kl[cur], Vl[cur], l31, hi, sw, qf, m_, l_, o0, o1);
      else     attn_tile_lds<1, true>(Kl[cur], Vl[cur], l31, hi, sw, qf, m_, l_, o0, o1);
    }
    __syncthreads();
    cur ^= 1;
  }
  #undef STAGE

  // ---- epilogue: O^T[d][q] -> out[b, q, h*64+d], fp32
  const float inv = 1.f / l_;
  const int b = head >> 4, h = head & 15;
  float* op = out + ((size_t)(b * 2048 + q0 + l31) << 10) + h * 64 + hi * 4;
  #pragma unroll
  for (int c = 0; c < 4; ++c){
    *(float4*)(op + 8 * c) =
        make_float4(o0[4*c]*inv, o0[4*c+1]*inv, o0[4*c+2]*inv, o0[4*c+3]*inv);
    *(float4*)(op + 32 + 8 * c) =
        make_float4(o1[4*c]*inv, o1[4*c+1]*inv, o1[4*c+2]*inv, o1[4*c+3]*inv);
  }
}

extern "C" void kernel_launch(void* const* d_in, const int* in_sizes, int n_in,
                              void* d_out, int out_size, void* d_ws, size_t ws_size,
                              hipStream_t stream){
  const float* x  = (const float*)d_in[0];
  const float* Wq = (const float*)d_in[1];
  const float* bq = (const float*)d_in[2];
  const float* Wk = (const float*)d_in[3];
  const float* bk = (const float*)d_in[4];
  const float* Wv = (const float*)d_in[5];
  const float* bv = (const float*)d_in[6];
  float* out = (float*)d_out;
  char* ws = (char*)d_ws;
  // ws layout (bytes): xs 16MB | wtq/wtk/wtv 2MB each | Q 16MB | K 16MB | Vt 16MB = 70MB
  unsigned short* xs  = (unsigned short*)(ws);
  unsigned short* wtq = (unsigned short*)(ws + 16777216);
  unsigned short* wtk = (unsigned short*)(ws + 18874368);
  unsigned short* wtv = (unsigned short*)(ws + 20971520);
  unsigned short* Qg  = (unsigned short*)(ws + 23068672);
  unsigned short* Kg  = (unsigned short*)(ws + 39845888);
  unsigned short* Vt  = (unsigned short*)(ws + 56623104);

  cvt_x<<<4096, 256, 0, stream>>>(x, xs);
  cvt_w<<<dim3(512, 3), 256, 0, stream>>>(Wq, Wk, Wv, wtq, wtk, wtv);
  proj_gemm<<<dim3(64, 8, 3), 256, 0, stream>>>(xs, wtq, wtk, wtv, bq, bk, bv, Qg, Kg, Vt);
  attn<<<1024, 256, 0, stream>>>(Qg, Kg, Vt, out);
}